// Round 6
// baseline (834.821 us; speedup 1.0000x reference)
//
#include <hip/hip_runtime.h>
#include <hip/hip_bf16.h>

// Problem constants
#define B_  64
#define N_  16384
#define S_  64      // NUM_PATCHES
#define K_  32      // PATCH_POINTS
#define C1_ 64
#define C2_ 128
#define C3_ 384
#define R_  (B_*S_*K_)   // 131072 rows
#define BN_EPS_ 1e-5f

// ws layout (float offsets)
#define PATCH_OFF 0
#define CENT_OFF  (R_*3)                      // 393216
#define NB1_ 512
#define P1_OFF    (CENT_OFF + B_*S_*3)        // 405504
#define SC1_OFF   (P1_OFF + NB1_*C1_*2)       // 471040
#define NB2_ 512
#define P2_OFF    (SC1_OFF + 2*C1_)           // 471168
#define SC2_OFF   (P2_OFF + NB2_*C2_*2)       // 602240
#define W2BF_OFF  (SC2_OFF + 2*C2_)           // 602496 (floats; holds 8192 shorts)
#define W3BF_OFF  (W2BF_OFF + 4096)           // 606592 (floats; holds 49152 shorts)
// end = 631168 floats (~2.52 MB) — below proven ws usage (733568 floats)

typedef short bf16x8 __attribute__((ext_vector_type(8)));
typedef float f32x4  __attribute__((ext_vector_type(4)));

static __device__ __forceinline__ unsigned short f2bf(float f) {
  unsigned u = __float_as_uint(f);
  unsigned r = (u + 0x7fffu + ((u >> 16) & 1u)) >> 16;   // RNE
  return (unsigned short)r;
}

// ---------------------------------------------------------------------------
// prep: convert W2 (128x64) and W3 (384x128) to bf16, row-major (plain).
// ---------------------------------------------------------------------------
__global__ void prep_kernel(const float* __restrict__ W2, const float* __restrict__ W3,
                            short* __restrict__ w2bf, short* __restrict__ w3bf) {
  int i = blockIdx.x * 256 + threadIdx.x;
  if (i < C2_*C1_) w2bf[i] = (short)f2bf(W2[i]);
  int j = i - C2_*C1_;
  if (j >= 0 && j < C3_*C2_) w3bf[j] = (short)f2bf(W3[j]);
}

// ---------------------------------------------------------------------------
// FPS: one block (1024 threads) per batch. 16 points/thread in registers.
// Per step: scan + wave lex-reduce -> 16 wave winners in LDS -> ALL threads
// redundantly reduce the 16 (broadcast reads) so the next centroid lives in
// registers. No serial t<16 phase, no cb round-trip. 2 barriers/step.
// Distance replicates XLA contraction: fma(dz,dz,fma(dy,dy,dx*dx)).
// ---------------------------------------------------------------------------
__global__ __launch_bounds__(1024) void fps_kernel(const float* __restrict__ x,
        float* __restrict__ centers, float* __restrict__ outCent) {
  int b = blockIdx.x;
  int t = threadIdx.x;
  const float* xb = x + (size_t)b * N_ * 3;
  float px[16], py[16], pz[16], dist[16];
#pragma unroll
  for (int j = 0; j < 16; ++j) {
    int n = j * 1024 + t;
    px[j] = xb[n*3+0]; py[j] = xb[n*3+1]; pz[j] = xb[n*3+2];
    dist[j] = 1e10f;
  }
  __shared__ float wd[16], wx[16], wy[16], wz[16];
  __shared__ int wi[16];
  // c_0 = point 0 (uniform broadcast load)
  float cx = xb[0], cy = xb[1], cz = xb[2];
  int lane = t & 63, wv = t >> 6;
  for (int s = 0; s < S_; ++s) {
    if (t == 0) {
      int task = b * S_ + s;
      centers[task*3+0] = cx; centers[task*3+1] = cy; centers[task*3+2] = cz;
      outCent[task*3+0] = cx; outCent[task*3+1] = cy; outCent[task*3+2] = cz;
    }
    float bd = -1.0f; int bn = 0; float bx = 0.f, by = 0.f, bz = 0.f;
#pragma unroll
    for (int j = 0; j < 16; ++j) {
      float dx = px[j]-cx, dy = py[j]-cy, dz = pz[j]-cz;
      float d = __builtin_fmaf(dz, dz, __builtin_fmaf(dy, dy, dx*dx));
      float dm = fminf(dist[j], d);
      dist[j] = dm;
      int n = j*1024 + t;
      if (dm > bd) { bd = dm; bn = n; bx = px[j]; by = py[j]; bz = pz[j]; }
    }
#pragma unroll
    for (int m = 1; m < 64; m <<= 1) {
      float od = __shfl_xor(bd, m, 64); int on = __shfl_xor(bn, m, 64);
      float ox = __shfl_xor(bx, m, 64), oy = __shfl_xor(by, m, 64), oz = __shfl_xor(bz, m, 64);
      if (od > bd || (od == bd && on < bn)) { bd = od; bn = on; bx = ox; by = oy; bz = oz; }
    }
    if (lane == 0) { wd[wv] = bd; wi[wv] = bn; wx[wv] = bx; wy[wv] = by; wz[wv] = bz; }
    __syncthreads();
    // all-thread redundant reduce of 16 wave winners (LDS broadcast reads)
    float gd = wd[0]; int gn = wi[0];
    float gx = wx[0], gy = wy[0], gz = wz[0];
#pragma unroll
    for (int w = 1; w < 16; ++w) {
      float od = wd[w]; int on = wi[w];
      if (od > gd || (od == gd && on < gn)) {
        gd = od; gn = on; gx = wx[w]; gy = wy[w]; gz = wz[w];
      }
    }
    cx = gx; cy = gy; cz = gz;
    __syncthreads();   // protect wd/wi for next step's writes
  }
}

// ---------------------------------------------------------------------------
// query_ball: one block (256 threads) per (b,s). Exact 32-NN via radix
// bisection (VALU count + shfl reduce) with AND/OR bit-skip and EARLY STOP:
// first pass whose count lands in [32,48] yields threshold CAND; collect
// the <=48 candidates and rank them exactly by (key, idx) — top-32 = exact
// reference set. Fallback to full exact-T path if the window is never hit.
// ---------------------------------------------------------------------------
__global__ __launch_bounds__(256) void qb_kernel(const float* __restrict__ x,
        const float* __restrict__ centers, float* __restrict__ patches) {
  int t = threadIdx.x;
  int task = blockIdx.x;
  int b = task >> 6;
  const float* xb = x + (size_t)b * N_ * 3;
  float cx = centers[task*3+0], cy = centers[task*3+1], cz = centers[task*3+2];
  float A = __builtin_fmaf(cz, cz, __builtin_fmaf(cy, cy, cx*cx));

  __shared__ unsigned int wcnt[40][4];
  __shared__ unsigned int wAnd[4], wOr[4];
  __shared__ unsigned int redMin[4];
  __shared__ unsigned int keyC[48];
  __shared__ int idxC[48];
  __shared__ int rankL[48];
  __shared__ int idxL[40];
  __shared__ int sortedIdx[32];
  __shared__ unsigned int cntA;
  if (t == 0) cntA = 0u;

  unsigned int key[64];
  unsigned int kA = 0xffffffffu, kO = 0u;
#pragma unroll
  for (int j = 0; j < 64; ++j) {
    int n = j * 256 + t;
    float qx = xb[n*3+0], qy = xb[n*3+1], qz = xb[n*3+2];
    float Bn = __builtin_fmaf(qz, qz, __builtin_fmaf(qy, qy, qx*qx));
    float dt = __builtin_fmaf(cz, qz, __builtin_fmaf(cy, qy, cx*qx));
    float d  = __builtin_fmaf(-2.0f, dt, A + Bn);
    unsigned int u = __float_as_uint(d);
    unsigned int k = (u & 0x80000000u) ? ~u : (u | 0x80000000u);
    key[j] = k; kA &= k; kO |= k;
  }
  int lane = t & 63, wv = t >> 6;

  // block-wide AND / OR of keys
#pragma unroll
  for (int m = 1; m < 64; m <<= 1) {
    kA &= (unsigned int)__shfl_xor((int)kA, m, 64);
    kO |= (unsigned int)__shfl_xor((int)kO, m, 64);
  }
  if (lane == 0) { wAnd[wv] = kA; wOr[wv] = kO; }
  __syncthreads();
  unsigned int gA = wAnd[0] & wAnd[1] & wAnd[2] & wAnd[3];
  unsigned int gO = wOr[0]  | wOr[1]  | wOr[2]  | wOr[3];
  unsigned int diff = gA ^ gO;      // varying bit positions

  // radix bisection (skip agreed bits, early-stop on count in [32,48])
  unsigned int result = 0u;
  unsigned int CAND = 0u;
  bool early = false;
  int pc = 0;
  for (int bit = 31; bit >= 0; --bit) {
    unsigned int msk = 1u << bit;
    if (!(diff & msk)) { result |= (gA & msk); continue; }
    unsigned int tryv = result | msk;
    int c = 0;
#pragma unroll
    for (int j = 0; j < 64; ++j) c += (key[j] < tryv) ? 1 : 0;
#pragma unroll
    for (int m = 1; m < 64; m <<= 1) c += __shfl_xor(c, m, 64);
    if (lane == 0) wcnt[pc][wv] = (unsigned int)c;
    __syncthreads();
    unsigned int tot = wcnt[pc][0] + wcnt[pc][1] + wcnt[pc][2] + wcnt[pc][3];
    if (tot >= 32u && tot <= 48u) { early = true; CAND = tryv; break; }
    if (tot < 32u) result = tryv;
    ++pc;
  }

  if (early) {
    // collect candidates (<=48), order arbitrary
#pragma unroll
    for (int j = 0; j < 64; ++j) {
      if (key[j] < CAND) {
        unsigned int p = atomicAdd(&cntA, 1u);
        keyC[p] = key[j];
        idxC[p] = j * 256 + t;
      }
    }
    __syncthreads();
    int tot = (int)cntA;
    if (t < tot) {
      unsigned int mk = keyC[t]; int mi = idxC[t];
      int rank = 0;
      for (int jj = 0; jj < tot; ++jj) {
        unsigned int ok = keyC[jj]; int oi = idxC[jj];
        rank += (ok < mk || (ok == mk && oi < mi)) ? 1 : 0;
      }
      rankL[t] = rank;
    }
    __syncthreads();
    if (t < tot && rankL[t] < 32) {
      int mi = idxC[t];
      int slot = 0;
      for (int jj = 0; jj < tot; ++jj)
        slot += (rankL[jj] < 32 && idxC[jj] < mi) ? 1 : 0;
      sortedIdx[slot] = mi;
    }
    __syncthreads();
  } else {
    unsigned int T = result;
    // exact count of strictly-less
    {
      int c = 0;
#pragma unroll
      for (int j = 0; j < 64; ++j) c += (key[j] < T) ? 1 : 0;
#pragma unroll
      for (int m = 1; m < 64; m <<= 1) c += __shfl_xor(c, m, 64);
      if (lane == 0) wcnt[pc][wv] = (unsigned int)c;
    }
    __syncthreads();
    unsigned int totLess = wcnt[pc][0] + wcnt[pc][1] + wcnt[pc][2] + wcnt[pc][3];

#pragma unroll
    for (int j = 0; j < 64; ++j) {
      if (key[j] < T) {
        unsigned int p = atomicAdd(&cntA, 1u);
        idxL[p] = j * 256 + t;
      }
    }

    int m_need = 32 - (int)totLess;   // >= 1 by construction
    int picked = -1;
    for (int r = 0; r < m_need; ++r) {
      int cand = 0x7fffffff;
#pragma unroll
      for (int j = 0; j < 64; ++j) {
        int n = j * 256 + t;
        if (key[j] == T && n > picked && n < cand) cand = n;
      }
#pragma unroll
      for (int m = 1; m < 64; m <<= 1) cand = min(cand, __shfl_xor(cand, m, 64));
      if (lane == 0) redMin[wv] = (unsigned int)cand;
      __syncthreads();
      int winner = (int)min(min(redMin[0], redMin[1]), min(redMin[2], redMin[3]));
      if (t == 0) idxL[(int)totLess + r] = winner;
      picked = winner;
      __syncthreads();
    }

    if (t < 32) {
      int v = idxL[t];
      int rank = 0;
#pragma unroll
      for (int j = 0; j < 32; ++j) rank += (idxL[j] < v) ? 1 : 0;
      sortedIdx[rank] = v;
    }
    __syncthreads();
  }

  if (t < 32) {
    int n = sortedIdx[t];
    float qx = xb[n*3+0], qy = xb[n*3+1], qz = xb[n*3+2];
    size_t row = (size_t)task * K_ + t;
    patches[row*3+0] = qx - cx;
    patches[row*3+1] = qy - cy;
    patches[row*3+2] = qz - cz;
  }
}

// ---------------------------------------------------------------------------
// stats1: per-channel sum / sumsq of h1 (512 blocks x 256 rows)
// ---------------------------------------------------------------------------
__global__ __launch_bounds__(256) void stats1_kernel(const float* __restrict__ patches,
        const float* __restrict__ W1, const float* __restrict__ b1,
        float* __restrict__ part) {
  int t = threadIdx.x;
  int o = t & 63, rg = t >> 6;
  float w0 = W1[o*3+0], w1 = W1[o*3+1], w2 = W1[o*3+2], bb = b1[o];
  int r0 = blockIdx.x * 256 + rg * 64;
  float s1 = 0.f, s2 = 0.f;
  for (int i = 0; i < 64; ++i) {
    const float* p = patches + (size_t)(r0 + i) * 3;
    float h = p[0]*w0 + p[1]*w1 + p[2]*w2 + bb;
    s1 += h; s2 += h*h;
  }
  __shared__ float red[4][64][2];
  red[rg][o][0] = s1; red[rg][o][1] = s2;
  __syncthreads();
  if (t < 64) {
    float a = red[0][t][0] + red[1][t][0] + red[2][t][0] + red[3][t][0];
    float c = red[0][t][1] + red[1][t][1] + red[2][t][1] + red[3][t][1];
    part[blockIdx.x*128 + t*2 + 0] = a;
    part[blockIdx.x*128 + t*2 + 1] = c;
  }
}

// ---------------------------------------------------------------------------
// finalize: deterministic sum of partials -> scale/shift (BN affine form).
// If bias != nullptr, folds a pre-BN linear bias into shift.
// ---------------------------------------------------------------------------
__global__ void finalize_kernel(const float* __restrict__ part, int nblk, int nch,
        const float* __restrict__ g, const float* __restrict__ be,
        const float* __restrict__ bias,
        float* __restrict__ scale, float* __restrict__ shift) {
  int o = threadIdx.x;
  if (o >= nch) return;
  double s1 = 0.0, s2 = 0.0;
  for (int i = 0; i < nblk; ++i) {
    s1 += (double)part[i*nch*2 + o*2 + 0];
    s2 += (double)part[i*nch*2 + o*2 + 1];
  }
  float m   = (float)(s1 / (double)R_);
  float eh2 = (float)(s2 / (double)R_);
  float v = eh2 - m*m;
  float rs = rsqrtf(v + BN_EPS_);
  float sc = g[o] * rs;
  scale[o] = sc;
  float sh = be[o] - m*sc;
  if (bias) sh += bias[o]*sc;
  shift[o] = sh;
}

// ---------------------------------------------------------------------------
// stats2: 512 blocks x 256 rows (2 tiles of 128): recompute a1 tile (LDS),
// h2 = a1@W2^T + b2 (fp32), per-channel sum/sumsq.
// ---------------------------------------------------------------------------
__global__ __launch_bounds__(256) void stats2_kernel(const float* __restrict__ patches,
        const float* __restrict__ W1, const float* __restrict__ b1,
        const float* __restrict__ sc1, const float* __restrict__ sh1,
        const float* __restrict__ W2, const float* __restrict__ b2,
        float* __restrict__ part) {
  __shared__ float a1L[128][68];
  __shared__ float red[2][128][2];
  int t = threadIdx.x;
  float4 wreg[16];
  const float4* w2r = (const float4*)(W2 + (t & 127)*64);
#pragma unroll
  for (int c = 0; c < 16; ++c) wreg[c] = w2r[c];
  float bb = b2[t & 127];
  float s1 = 0.f, s2 = 0.f;
  int rg = t >> 7;
  for (int tile = 0; tile < 2; ++tile) {
    int r0 = blockIdx.x * 256 + tile * 128;
    {
      int r = t & 127, oh = t >> 7;
      const float* p = patches + (size_t)(r0 + r) * 3;
      float p0 = p[0], p1 = p[1], p2 = p[2];
#pragma unroll
      for (int j = 0; j < 32; ++j) {
        int o = oh*32 + j;
        float h = p0*W1[o*3] + p1*W1[o*3+1] + p2*W1[o*3+2] + b1[o];
        a1L[r][o] = fmaxf(h*sc1[o] + sh1[o], 0.f);
      }
    }
    __syncthreads();
    for (int i = 0; i < 64; ++i) {
      int r = rg*64 + i;
      float acc = bb;
      const float4* a4 = (const float4*)(&a1L[r][0]);
#pragma unroll
      for (int c = 0; c < 16; ++c) {
        float4 a = a4[c];
        acc += a.x*wreg[c].x; acc += a.y*wreg[c].y;
        acc += a.z*wreg[c].z; acc += a.w*wreg[c].w;
      }
      s1 += acc; s2 += acc*acc;
    }
    __syncthreads();
  }
  red[rg][t & 127][0] = s1; red[rg][t & 127][1] = s2;
  __syncthreads();
  if (t < 128) {
    part[blockIdx.x*256 + t*2 + 0] = red[0][t][0] + red[1][t][0];
    part[blockIdx.x*256 + t*2 + 1] = red[0][t][1] + red[1][t][1];
  }
}

// ---------------------------------------------------------------------------
// embed (MFMA): 4 tasks/block (M=128 rows), 256 threads (4 waves, 1 task/wave).
// ---------------------------------------------------------------------------
__global__ __launch_bounds__(256) void embed_kernel(
        const float* __restrict__ patches,
        const float* __restrict__ W1, const float* __restrict__ b1,
        const float* __restrict__ sc1, const float* __restrict__ sh1,
        const short* __restrict__ w2bf, const float* __restrict__ sc2,
        const float* __restrict__ sh2f,
        const short* __restrict__ w3bf, const float* __restrict__ b3,
        float* __restrict__ out) {
  __shared__ char lds[49152];   // a1L @0 (16KB), a2L @16384 (32KB)
  int t = threadIdx.x;
  int l = t & 63, w = t >> 6;
  int lo = l & 15, hi = l >> 4;

  // ---- P1 ----
  {
    int row = t >> 1, half = t & 1;
    const float* p = patches + ((size_t)blockIdx.x*128 + row)*3;
    float p0 = p[0], p1 = p[1], p2 = p[2];
    int swz = (row & 7) << 4;
    char* dst = lds + row*128;
#pragma unroll
    for (int g = 0; g < 4; ++g) {
      unsigned short pk[8];
#pragma unroll
      for (int j = 0; j < 8; ++j) {
        int o = half*32 + g*8 + j;
        float h = p0*W1[o*3] + p1*W1[o*3+1] + p2*W1[o*3+2] + b1[o];
        pk[j] = f2bf(fmaxf(h*sc1[o] + sh1[o], 0.f));
      }
      int4 v;
      v.x = pk[0] | (pk[1]<<16); v.y = pk[2] | (pk[3]<<16);
      v.z = pk[4] | (pk[5]<<16); v.w = pk[6] | (pk[7]<<16);
      *(int4*)(dst + (((half*64 + g*16)) ^ swz)) = v;
    }
  }
  __syncthreads();

  // ---- P2 ----
  {
    bf16x8 af[2][2];
#pragma unroll
    for (int mt = 0; mt < 2; ++mt) {
      int row = w*32 + mt*16 + lo;
#pragma unroll
      for (int ks = 0; ks < 2; ++ks)
        af[mt][ks] = *(const bf16x8*)(lds + row*128 + ((ks*64 + hi*16) ^ ((row&7)<<4)));
    }
#pragma unroll
    for (int nt = 0; nt < 8; ++nt) {
      f32x4 acc0 = {0.f,0.f,0.f,0.f}, acc1 = {0.f,0.f,0.f,0.f};
      int n = nt*16 + lo;
#pragma unroll
      for (int ks = 0; ks < 2; ++ks) {
        bf16x8 bfv = *(const bf16x8*)(w2bf + n*64 + ks*32 + hi*8);
        acc0 = __builtin_amdgcn_mfma_f32_16x16x32_bf16(af[0][ks], bfv, acc0, 0, 0, 0);
        acc1 = __builtin_amdgcn_mfma_f32_16x16x32_bf16(af[1][ks], bfv, acc1, 0, 0, 0);
      }
      float sc = sc2[n], sh = sh2f[n];
#pragma unroll
      for (int mt = 0; mt < 2; ++mt) {
        f32x4 c = mt ? acc1 : acc0;
#pragma unroll
        for (int r = 0; r < 4; ++r) {
          int row = w*32 + mt*16 + hi*4 + r;
          unsigned short v = f2bf(fmaxf(c[r]*sc + sh, 0.f));
          *(short*)(lds + 16384 + row*256 + ((n*2) ^ ((row&7)<<4))) = (short)v;
        }
      }
    }
  }
  __syncthreads();

  // ---- P3 ----
  {
    bf16x8 af[2][4];
#pragma unroll
    for (int mt = 0; mt < 2; ++mt) {
      int row = w*32 + mt*16 + lo;
#pragma unroll
      for (int ks = 0; ks < 4; ++ks)
        af[mt][ks] = *(const bf16x8*)(lds + 16384 + row*256 + ((ks*64 + hi*16) ^ ((row&7)<<4)));
    }
    size_t gtask = (size_t)blockIdx.x*4 + w;
#pragma unroll 4
    for (int nt = 0; nt < 24; ++nt) {
      f32x4 acc0 = {0.f,0.f,0.f,0.f}, acc1 = {0.f,0.f,0.f,0.f};
      int e = nt*16 + lo;
#pragma unroll
      for (int ks = 0; ks < 4; ++ks) {
        bf16x8 bfv = *(const bf16x8*)(w3bf + e*128 + ks*32 + hi*8);
        acc0 = __builtin_amdgcn_mfma_f32_16x16x32_bf16(af[0][ks], bfv, acc0, 0, 0, 0);
        acc1 = __builtin_amdgcn_mfma_f32_16x16x32_bf16(af[1][ks], bfv, acc1, 0, 0, 0);
      }
      float m0 = fmaxf(fmaxf(acc0[0], acc0[1]), fmaxf(acc0[2], acc0[3]));
      float m1 = fmaxf(fmaxf(acc1[0], acc1[1]), fmaxf(acc1[2], acc1[3]));
      float m = fmaxf(m0, m1);
      m = fmaxf(m, __shfl_xor(m, 16, 64));
      m = fmaxf(m, __shfl_xor(m, 32, 64));
      if (l < 16) out[gtask*C3_ + e] = m + b3[e];
    }
  }
}

// ---------------------------------------------------------------------------
extern "C" void kernel_launch(void* const* d_in, const int* in_sizes, int n_in,
                              void* d_out, int out_size, void* d_ws, size_t ws_size,
                              hipStream_t stream) {
  (void)in_sizes; (void)n_in; (void)out_size; (void)ws_size;
  const float* x   = (const float*)d_in[0];
  const float* W1  = (const float*)d_in[1];
  const float* b1  = (const float*)d_in[2];
  const float* g1  = (const float*)d_in[3];
  const float* be1 = (const float*)d_in[4];
  const float* W2  = (const float*)d_in[5];
  const float* b2  = (const float*)d_in[6];
  const float* g2  = (const float*)d_in[7];
  const float* be2 = (const float*)d_in[8];
  const float* W3  = (const float*)d_in[9];
  const float* b3  = (const float*)d_in[10];
  float* out = (float*)d_out;
  float* ws  = (float*)d_ws;

  float* patches = ws + PATCH_OFF;
  float* centers = ws + CENT_OFF;
  float* part1   = ws + P1_OFF;
  float* sc1     = ws + SC1_OFF; float* sh1 = sc1 + C1_;
  float* part2   = ws + P2_OFF;
  float* sc2     = ws + SC2_OFF; float* sh2 = sc2 + C2_;
  short* w2bf    = (short*)(ws + W2BF_OFF);
  short* w3bf    = (short*)(ws + W3BF_OFF);
  float* outCent = out + (size_t)B_*S_*C3_;

  prep_kernel<<<dim3((C2_*C1_ + C3_*C2_)/256), dim3(256), 0, stream>>>(W2, W3, w2bf, w3bf);
  fps_kernel<<<dim3(B_), dim3(1024), 0, stream>>>(x, centers, outCent);
  qb_kernel<<<dim3(4096), dim3(256), 0, stream>>>(x, centers, patches);
  stats1_kernel<<<dim3(NB1_), dim3(256), 0, stream>>>(patches, W1, b1, part1);
  finalize_kernel<<<dim3(1), dim3(64), 0, stream>>>(part1, NB1_, C1_, g1, be1, nullptr, sc1, sh1);
  stats2_kernel<<<dim3(NB2_), dim3(256), 0, stream>>>(patches, W1, b1, sc1, sh1, W2, b2, part2);
  finalize_kernel<<<dim3(1), dim3(128), 0, stream>>>(part2, NB2_, C2_, g2, be2, b2, sc2, sh2);
  embed_kernel<<<dim3(1024), dim3(256), 0, stream>>>(patches, W1, b1, sc1, sh1,
                                                     w2bf, sc2, sh2, w3bf, b3, out);
}

// Round 7
// 806.880 us; speedup vs baseline: 1.0346x; 1.0346x over previous
//
#include <hip/hip_runtime.h>
#include <hip/hip_bf16.h>

// Problem constants
#define B_  64
#define N_  16384
#define S_  64      // NUM_PATCHES
#define K_  32      // PATCH_POINTS
#define C1_ 64
#define C2_ 128
#define C3_ 384
#define R_  (B_*S_*K_)   // 131072 rows
#define BN_EPS_ 1e-5f

// ws layout (float offsets)
#define PATCH_OFF 0
#define CENT_OFF  (R_*3)                      // 393216
#define NB1_ 512
#define P1_OFF    (CENT_OFF + B_*S_*3)        // 405504
#define SC1_OFF   (P1_OFF + NB1_*C1_*2)       // 471040
#define NB2_ 512
#define P2_OFF    (SC1_OFF + 2*C1_)           // 471168
#define SC2_OFF   (P2_OFF + NB2_*C2_*2)       // 602240
#define W2BF_OFF  (SC2_OFF + 2*C2_)           // 602496 (floats; holds 8192 shorts)
#define W3BF_OFF  (W2BF_OFF + 4096)           // 606592 (floats; holds 49152 shorts)
// end = 631168 floats (~2.52 MB)

typedef short bf16x8 __attribute__((ext_vector_type(8)));
typedef float f32x4  __attribute__((ext_vector_type(4)));

static __device__ __forceinline__ unsigned short f2bf(float f) {
  unsigned u = __float_as_uint(f);
  unsigned r = (u + 0x7fffu + ((u >> 16) & 1u)) >> 16;   // RNE
  return (unsigned short)r;
}

// ---------------------------------------------------------------------------
// prep: convert W2 (128x64) and W3 (384x128) to bf16, row-major (plain).
// ---------------------------------------------------------------------------
__global__ void prep_kernel(const float* __restrict__ W2, const float* __restrict__ W3,
                            short* __restrict__ w2bf, short* __restrict__ w3bf) {
  int i = blockIdx.x * 256 + threadIdx.x;
  if (i < C2_*C1_) w2bf[i] = (short)f2bf(W2[i]);
  int j = i - C2_*C1_;
  if (j >= 0 && j < C3_*C2_) w3bf[j] = (short)f2bf(W3[j]);
}

// ---------------------------------------------------------------------------
// FPS: one block (1024 threads) per batch. 16 points/thread in registers.
// __launch_bounds__(1024,4): VGPR cap 128 -> px/py/pz/dist stay in registers
// (at the default cap of 64 they spilled to scratch -> 217us latency-bound).
// Reduce carries only (d,n); winner coords re-fetched via broadcast L1 load
// (bit-identical). Double-buffered wave-winner slots -> ONE barrier/step.
// Distance replicates XLA contraction: fma(dz,dz,fma(dy,dy,dx*dx)).
// ---------------------------------------------------------------------------
__global__ __launch_bounds__(1024, 4) void fps_kernel(const float* __restrict__ x,
        float* __restrict__ centers, float* __restrict__ outCent) {
  int b = blockIdx.x;
  int t = threadIdx.x;
  const float* xb = x + (size_t)b * N_ * 3;
  float px[16], py[16], pz[16], dist[16];
#pragma unroll
  for (int j = 0; j < 16; ++j) {
    int n = j * 1024 + t;
    px[j] = xb[n*3+0]; py[j] = xb[n*3+1]; pz[j] = xb[n*3+2];
    dist[j] = 1e10f;
  }
  __shared__ float wd[2][16];
  __shared__ int   wi[2][16];
  float cx = xb[0], cy = xb[1], cz = xb[2];
  int lane = t & 63, wv = t >> 6;
  for (int s = 0; s < S_; ++s) {
    if (t == 0) {
      int task = b * S_ + s;
      centers[task*3+0] = cx; centers[task*3+1] = cy; centers[task*3+2] = cz;
      outCent[task*3+0] = cx; outCent[task*3+1] = cy; outCent[task*3+2] = cz;
    }
    float bd = -1.0f; int bn = 0;
#pragma unroll
    for (int j = 0; j < 16; ++j) {
      float dx = px[j]-cx, dy = py[j]-cy, dz = pz[j]-cz;
      float d = __builtin_fmaf(dz, dz, __builtin_fmaf(dy, dy, dx*dx));
      float dm = fminf(dist[j], d);
      dist[j] = dm;
      int n = j*1024 + t;
      if (dm > bd) { bd = dm; bn = n; }
    }
#pragma unroll
    for (int m = 1; m < 64; m <<= 1) {
      float od = __shfl_xor(bd, m, 64); int on = __shfl_xor(bn, m, 64);
      if (od > bd || (od == bd && on < bn)) { bd = od; bn = on; }
    }
    int buf = s & 1;
    if (lane == 0) { wd[buf][wv] = bd; wi[buf][wv] = bn; }
    __syncthreads();
    // depth-4 register tree over the 16 wave winners (broadcast LDS reads)
    float td[16]; int ti[16];
#pragma unroll
    for (int w = 0; w < 16; ++w) { td[w] = wd[buf][w]; ti[w] = wi[buf][w]; }
#pragma unroll
    for (int off = 8; off >= 1; off >>= 1) {
#pragma unroll
      for (int w = 0; w < 8; ++w) {
        if (w < off) {
          if (td[w+off] > td[w] || (td[w+off] == td[w] && ti[w+off] < ti[w])) {
            td[w] = td[w+off]; ti[w] = ti[w+off];
          }
        }
      }
    }
    int gn = ti[0];
    cx = xb[gn*3+0]; cy = xb[gn*3+1]; cz = xb[gn*3+2];
    // no second barrier: next step writes wd[buf^1]
  }
}

// ---------------------------------------------------------------------------
// query_ball: one block (512 threads, 8 waves) per (b,s). 32 keys/thread in
// registers (no spill at VGPR cap 128). Exact 32-NN via radix bisection with
// AND/OR bit-skip and early-stop window [32,48]; candidate ranking by
// (key, idx) reproduces exact reference top-k; canonical index sort.
// ---------------------------------------------------------------------------
__global__ __launch_bounds__(512, 4) void qb_kernel(const float* __restrict__ x,
        const float* __restrict__ centers, float* __restrict__ patches) {
  int t = threadIdx.x;
  int task = blockIdx.x;
  int b = task >> 6;
  const float* xb = x + (size_t)b * N_ * 3;
  float cx = centers[task*3+0], cy = centers[task*3+1], cz = centers[task*3+2];
  float A = __builtin_fmaf(cz, cz, __builtin_fmaf(cy, cy, cx*cx));

  __shared__ unsigned int wcnt[40][8];
  __shared__ unsigned int wAnd[8], wOr[8];
  __shared__ unsigned int redMin[8];
  __shared__ unsigned int keyC[48];
  __shared__ int idxC[48];
  __shared__ int rankL[48];
  __shared__ int idxL[40];
  __shared__ int sortedIdx[32];
  __shared__ unsigned int cntA;
  if (t == 0) cntA = 0u;

  unsigned int key[32];
  unsigned int kA = 0xffffffffu, kO = 0u;
#pragma unroll
  for (int j = 0; j < 32; ++j) {
    int n = j * 512 + t;
    float qx = xb[n*3+0], qy = xb[n*3+1], qz = xb[n*3+2];
    float Bn = __builtin_fmaf(qz, qz, __builtin_fmaf(qy, qy, qx*qx));
    float dt = __builtin_fmaf(cz, qz, __builtin_fmaf(cy, qy, cx*qx));
    float d  = __builtin_fmaf(-2.0f, dt, A + Bn);
    unsigned int u = __float_as_uint(d);
    unsigned int k = (u & 0x80000000u) ? ~u : (u | 0x80000000u);
    key[j] = k; kA &= k; kO |= k;
  }
  int lane = t & 63, wv = t >> 6;

  // block-wide AND / OR of keys
#pragma unroll
  for (int m = 1; m < 64; m <<= 1) {
    kA &= (unsigned int)__shfl_xor((int)kA, m, 64);
    kO |= (unsigned int)__shfl_xor((int)kO, m, 64);
  }
  if (lane == 0) { wAnd[wv] = kA; wOr[wv] = kO; }
  __syncthreads();
  unsigned int gA = wAnd[0] & wAnd[1] & wAnd[2] & wAnd[3]
                  & wAnd[4] & wAnd[5] & wAnd[6] & wAnd[7];
  unsigned int gO = wOr[0] | wOr[1] | wOr[2] | wOr[3]
                  | wOr[4] | wOr[5] | wOr[6] | wOr[7];
  unsigned int diff = gA ^ gO;      // varying bit positions

  // radix bisection (skip agreed bits, early-stop on count in [32,48])
  unsigned int result = 0u;
  unsigned int CAND = 0u;
  bool early = false;
  int pc = 0;
  for (int bit = 31; bit >= 0; --bit) {
    unsigned int msk = 1u << bit;
    if (!(diff & msk)) { result |= (gA & msk); continue; }
    unsigned int tryv = result | msk;
    int c = 0;
#pragma unroll
    for (int j = 0; j < 32; ++j) c += (key[j] < tryv) ? 1 : 0;
#pragma unroll
    for (int m = 1; m < 64; m <<= 1) c += __shfl_xor(c, m, 64);
    if (lane == 0) wcnt[pc][wv] = (unsigned int)c;
    __syncthreads();
    unsigned int tot = 0;
#pragma unroll
    for (int w = 0; w < 8; ++w) tot += wcnt[pc][w];
    if (tot >= 32u && tot <= 48u) { early = true; CAND = tryv; break; }
    if (tot < 32u) result = tryv;
    ++pc;
  }

  if (early) {
    // collect candidates (<=48), order arbitrary (canonicalized below)
#pragma unroll
    for (int j = 0; j < 32; ++j) {
      if (key[j] < CAND) {
        unsigned int p = atomicAdd(&cntA, 1u);
        keyC[p] = key[j];
        idxC[p] = j * 512 + t;
      }
    }
    __syncthreads();
    int tot = (int)cntA;
    if (t < tot) {
      unsigned int mk = keyC[t]; int mi = idxC[t];
      int rank = 0;
      for (int jj = 0; jj < tot; ++jj) {
        unsigned int ok = keyC[jj]; int oi = idxC[jj];
        rank += (ok < mk || (ok == mk && oi < mi)) ? 1 : 0;
      }
      rankL[t] = rank;
    }
    __syncthreads();
    if (t < tot && rankL[t] < 32) {
      int mi = idxC[t];
      int slot = 0;
      for (int jj = 0; jj < tot; ++jj)
        slot += (rankL[jj] < 32 && idxC[jj] < mi) ? 1 : 0;
      sortedIdx[slot] = mi;
    }
    __syncthreads();
  } else {
    unsigned int T = result;
    // exact count of strictly-less
    {
      int c = 0;
#pragma unroll
      for (int j = 0; j < 32; ++j) c += (key[j] < T) ? 1 : 0;
#pragma unroll
      for (int m = 1; m < 64; m <<= 1) c += __shfl_xor(c, m, 64);
      if (lane == 0) wcnt[pc][wv] = (unsigned int)c;
    }
    __syncthreads();
    unsigned int totLess = 0;
#pragma unroll
    for (int w = 0; w < 8; ++w) totLess += wcnt[pc][w];

#pragma unroll
    for (int j = 0; j < 32; ++j) {
      if (key[j] < T) {
        unsigned int p = atomicAdd(&cntA, 1u);
        idxL[p] = j * 512 + t;
      }
    }

    int m_need = 32 - (int)totLess;   // >= 1 by construction
    int picked = -1;
    for (int r = 0; r < m_need; ++r) {
      int cand = 0x7fffffff;
#pragma unroll
      for (int j = 0; j < 32; ++j) {
        int n = j * 512 + t;
        if (key[j] == T && n > picked && n < cand) cand = n;
      }
#pragma unroll
      for (int m = 1; m < 64; m <<= 1) cand = min(cand, __shfl_xor(cand, m, 64));
      if (lane == 0) redMin[wv] = (unsigned int)cand;
      __syncthreads();
      unsigned int wmin = redMin[0];
#pragma unroll
      for (int w = 1; w < 8; ++w) wmin = min(wmin, redMin[w]);
      int winner = (int)wmin;
      if (t == 0) idxL[(int)totLess + r] = winner;
      picked = winner;
      __syncthreads();
    }

    if (t < 32) {
      int v = idxL[t];
      int rank = 0;
#pragma unroll
      for (int j = 0; j < 32; ++j) rank += (idxL[j] < v) ? 1 : 0;
      sortedIdx[rank] = v;
    }
    __syncthreads();
  }

  if (t < 32) {
    int n = sortedIdx[t];
    float qx = xb[n*3+0], qy = xb[n*3+1], qz = xb[n*3+2];
    size_t row = (size_t)task * K_ + t;
    patches[row*3+0] = qx - cx;
    patches[row*3+1] = qy - cy;
    patches[row*3+2] = qz - cz;
  }
}

// ---------------------------------------------------------------------------
// stats1: per-channel sum / sumsq of h1 (512 blocks x 256 rows)
// ---------------------------------------------------------------------------
__global__ __launch_bounds__(256) void stats1_kernel(const float* __restrict__ patches,
        const float* __restrict__ W1, const float* __restrict__ b1,
        float* __restrict__ part) {
  int t = threadIdx.x;
  int o = t & 63, rg = t >> 6;
  float w0 = W1[o*3+0], w1 = W1[o*3+1], w2 = W1[o*3+2], bb = b1[o];
  int r0 = blockIdx.x * 256 + rg * 64;
  float s1 = 0.f, s2 = 0.f;
  for (int i = 0; i < 64; ++i) {
    const float* p = patches + (size_t)(r0 + i) * 3;
    float h = p[0]*w0 + p[1]*w1 + p[2]*w2 + bb;
    s1 += h; s2 += h*h;
  }
  __shared__ float red[4][64][2];
  red[rg][o][0] = s1; red[rg][o][1] = s2;
  __syncthreads();
  if (t < 64) {
    float a = red[0][t][0] + red[1][t][0] + red[2][t][0] + red[3][t][0];
    float c = red[0][t][1] + red[1][t][1] + red[2][t][1] + red[3][t][1];
    part[blockIdx.x*128 + t*2 + 0] = a;
    part[blockIdx.x*128 + t*2 + 1] = c;
  }
}

// ---------------------------------------------------------------------------
// finalize: deterministic sum of partials -> scale/shift (BN affine form).
// If bias != nullptr, folds a pre-BN linear bias into shift.
// ---------------------------------------------------------------------------
__global__ void finalize_kernel(const float* __restrict__ part, int nblk, int nch,
        const float* __restrict__ g, const float* __restrict__ be,
        const float* __restrict__ bias,
        float* __restrict__ scale, float* __restrict__ shift) {
  int o = threadIdx.x;
  if (o >= nch) return;
  double s1 = 0.0, s2 = 0.0;
  for (int i = 0; i < nblk; ++i) {
    s1 += (double)part[i*nch*2 + o*2 + 0];
    s2 += (double)part[i*nch*2 + o*2 + 1];
  }
  float m   = (float)(s1 / (double)R_);
  float eh2 = (float)(s2 / (double)R_);
  float v = eh2 - m*m;
  float rs = rsqrtf(v + BN_EPS_);
  float sc = g[o] * rs;
  scale[o] = sc;
  float sh = be[o] - m*sc;
  if (bias) sh += bias[o]*sc;
  shift[o] = sh;
}

// ---------------------------------------------------------------------------
// stats2: 512 blocks x 256 rows (2 tiles of 128): recompute a1 tile (LDS),
// h2 = a1@W2^T + b2 (fp32), per-channel sum/sumsq.
// ---------------------------------------------------------------------------
__global__ __launch_bounds__(256) void stats2_kernel(const float* __restrict__ patches,
        const float* __restrict__ W1, const float* __restrict__ b1,
        const float* __restrict__ sc1, const float* __restrict__ sh1,
        const float* __restrict__ W2, const float* __restrict__ b2,
        float* __restrict__ part) {
  __shared__ float a1L[128][68];
  __shared__ float red[2][128][2];
  int t = threadIdx.x;
  float4 wreg[16];
  const float4* w2r = (const float4*)(W2 + (t & 127)*64);
#pragma unroll
  for (int c = 0; c < 16; ++c) wreg[c] = w2r[c];
  float bb = b2[t & 127];
  float s1 = 0.f, s2 = 0.f;
  int rg = t >> 7;
  for (int tile = 0; tile < 2; ++tile) {
    int r0 = blockIdx.x * 256 + tile * 128;
    {
      int r = t & 127, oh = t >> 7;
      const float* p = patches + (size_t)(r0 + r) * 3;
      float p0 = p[0], p1 = p[1], p2 = p[2];
#pragma unroll
      for (int j = 0; j < 32; ++j) {
        int o = oh*32 + j;
        float h = p0*W1[o*3] + p1*W1[o*3+1] + p2*W1[o*3+2] + b1[o];
        a1L[r][o] = fmaxf(h*sc1[o] + sh1[o], 0.f);
      }
    }
    __syncthreads();
    for (int i = 0; i < 64; ++i) {
      int r = rg*64 + i;
      float acc = bb;
      const float4* a4 = (const float4*)(&a1L[r][0]);
#pragma unroll
      for (int c = 0; c < 16; ++c) {
        float4 a = a4[c];
        acc += a.x*wreg[c].x; acc += a.y*wreg[c].y;
        acc += a.z*wreg[c].z; acc += a.w*wreg[c].w;
      }
      s1 += acc; s2 += acc*acc;
    }
    __syncthreads();
  }
  red[rg][t & 127][0] = s1; red[rg][t & 127][1] = s2;
  __syncthreads();
  if (t < 128) {
    part[blockIdx.x*256 + t*2 + 0] = red[0][t][0] + red[1][t][0];
    part[blockIdx.x*256 + t*2 + 1] = red[0][t][1] + red[1][t][1];
  }
}

// ---------------------------------------------------------------------------
// embed (MFMA): 4 tasks/block (M=128 rows), 256 threads (4 waves, 1 task/wave).
// ---------------------------------------------------------------------------
__global__ __launch_bounds__(256) void embed_kernel(
        const float* __restrict__ patches,
        const float* __restrict__ W1, const float* __restrict__ b1,
        const float* __restrict__ sc1, const float* __restrict__ sh1,
        const short* __restrict__ w2bf, const float* __restrict__ sc2,
        const float* __restrict__ sh2f,
        const short* __restrict__ w3bf, const float* __restrict__ b3,
        float* __restrict__ out) {
  __shared__ char lds[49152];   // a1L @0 (16KB), a2L @16384 (32KB)
  int t = threadIdx.x;
  int l = t & 63, w = t >> 6;
  int lo = l & 15, hi = l >> 4;

  // ---- P1 ----
  {
    int row = t >> 1, half = t & 1;
    const float* p = patches + ((size_t)blockIdx.x*128 + row)*3;
    float p0 = p[0], p1 = p[1], p2 = p[2];
    int swz = (row & 7) << 4;
    char* dst = lds + row*128;
#pragma unroll
    for (int g = 0; g < 4; ++g) {
      unsigned short pk[8];
#pragma unroll
      for (int j = 0; j < 8; ++j) {
        int o = half*32 + g*8 + j;
        float h = p0*W1[o*3] + p1*W1[o*3+1] + p2*W1[o*3+2] + b1[o];
        pk[j] = f2bf(fmaxf(h*sc1[o] + sh1[o], 0.f));
      }
      int4 v;
      v.x = pk[0] | (pk[1]<<16); v.y = pk[2] | (pk[3]<<16);
      v.z = pk[4] | (pk[5]<<16); v.w = pk[6] | (pk[7]<<16);
      *(int4*)(dst + (((half*64 + g*16)) ^ swz)) = v;
    }
  }
  __syncthreads();

  // ---- P2 ----
  {
    bf16x8 af[2][2];
#pragma unroll
    for (int mt = 0; mt < 2; ++mt) {
      int row = w*32 + mt*16 + lo;
#pragma unroll
      for (int ks = 0; ks < 2; ++ks)
        af[mt][ks] = *(const bf16x8*)(lds + row*128 + ((ks*64 + hi*16) ^ ((row&7)<<4)));
    }
#pragma unroll
    for (int nt = 0; nt < 8; ++nt) {
      f32x4 acc0 = {0.f,0.f,0.f,0.f}, acc1 = {0.f,0.f,0.f,0.f};
      int n = nt*16 + lo;
#pragma unroll
      for (int ks = 0; ks < 2; ++ks) {
        bf16x8 bfv = *(const bf16x8*)(w2bf + n*64 + ks*32 + hi*8);
        acc0 = __builtin_amdgcn_mfma_f32_16x16x32_bf16(af[0][ks], bfv, acc0, 0, 0, 0);
        acc1 = __builtin_amdgcn_mfma_f32_16x16x32_bf16(af[1][ks], bfv, acc1, 0, 0, 0);
      }
      float sc = sc2[n], sh = sh2f[n];
#pragma unroll
      for (int mt = 0; mt < 2; ++mt) {
        f32x4 c = mt ? acc1 : acc0;
#pragma unroll
        for (int r = 0; r < 4; ++r) {
          int row = w*32 + mt*16 + hi*4 + r;
          unsigned short v = f2bf(fmaxf(c[r]*sc + sh, 0.f));
          *(short*)(lds + 16384 + row*256 + ((n*2) ^ ((row&7)<<4))) = (short)v;
        }
      }
    }
  }
  __syncthreads();

  // ---- P3 ----
  {
    bf16x8 af[2][4];
#pragma unroll
    for (int mt = 0; mt < 2; ++mt) {
      int row = w*32 + mt*16 + lo;
#pragma unroll
      for (int ks = 0; ks < 4; ++ks)
        af[mt][ks] = *(const bf16x8*)(lds + 16384 + row*256 + ((ks*64 + hi*16) ^ ((row&7)<<4)));
    }
    size_t gtask = (size_t)blockIdx.x*4 + w;
#pragma unroll 4
    for (int nt = 0; nt < 24; ++nt) {
      f32x4 acc0 = {0.f,0.f,0.f,0.f}, acc1 = {0.f,0.f,0.f,0.f};
      int e = nt*16 + lo;
#pragma unroll
      for (int ks = 0; ks < 4; ++ks) {
        bf16x8 bfv = *(const bf16x8*)(w3bf + e*128 + ks*32 + hi*8);
        acc0 = __builtin_amdgcn_mfma_f32_16x16x32_bf16(af[0][ks], bfv, acc0, 0, 0, 0);
        acc1 = __builtin_amdgcn_mfma_f32_16x16x32_bf16(af[1][ks], bfv, acc1, 0, 0, 0);
      }
      float m0 = fmaxf(fmaxf(acc0[0], acc0[1]), fmaxf(acc0[2], acc0[3]));
      float m1 = fmaxf(fmaxf(acc1[0], acc1[1]), fmaxf(acc1[2], acc1[3]));
      float m = fmaxf(m0, m1);
      m = fmaxf(m, __shfl_xor(m, 16, 64));
      m = fmaxf(m, __shfl_xor(m, 32, 64));
      if (l < 16) out[gtask*C3_ + e] = m + b3[e];
    }
  }
}

// ---------------------------------------------------------------------------
extern "C" void kernel_launch(void* const* d_in, const int* in_sizes, int n_in,
                              void* d_out, int out_size, void* d_ws, size_t ws_size,
                              hipStream_t stream) {
  (void)in_sizes; (void)n_in; (void)out_size; (void)ws_size;
  const float* x   = (const float*)d_in[0];
  const float* W1  = (const float*)d_in[1];
  const float* b1  = (const float*)d_in[2];
  const float* g1  = (const float*)d_in[3];
  const float* be1 = (const float*)d_in[4];
  const float* W2  = (const float*)d_in[5];
  const float* b2  = (const float*)d_in[6];
  const float* g2  = (const float*)d_in[7];
  const float* be2 = (const float*)d_in[8];
  const float* W3  = (const float*)d_in[9];
  const float* b3  = (const float*)d_in[10];
  float* out = (float*)d_out;
  float* ws  = (float*)d_ws;

  float* patches = ws + PATCH_OFF;
  float* centers = ws + CENT_OFF;
  float* part1   = ws + P1_OFF;
  float* sc1     = ws + SC1_OFF; float* sh1 = sc1 + C1_;
  float* part2   = ws + P2_OFF;
  float* sc2     = ws + SC2_OFF; float* sh2 = sc2 + C2_;
  short* w2bf    = (short*)(ws + W2BF_OFF);
  short* w3bf    = (short*)(ws + W3BF_OFF);
  float* outCent = out + (size_t)B_*S_*C3_;

  prep_kernel<<<dim3((C2_*C1_ + C3_*C2_)/256), dim3(256), 0, stream>>>(W2, W3, w2bf, w3bf);
  fps_kernel<<<dim3(B_), dim3(1024), 0, stream>>>(x, centers, outCent);
  qb_kernel<<<dim3(4096), dim3(512), 0, stream>>>(x, centers, patches);
  stats1_kernel<<<dim3(NB1_), dim3(256), 0, stream>>>(patches, W1, b1, part1);
  finalize_kernel<<<dim3(1), dim3(64), 0, stream>>>(part1, NB1_, C1_, g1, be1, nullptr, sc1, sh1);
  stats2_kernel<<<dim3(NB2_), dim3(256), 0, stream>>>(patches, W1, b1, sc1, sh1, W2, b2, part2);
  finalize_kernel<<<dim3(1), dim3(128), 0, stream>>>(part2, NB2_, C2_, g2, be2, b2, sc2, sh2);
  embed_kernel<<<dim3(1024), dim3(256), 0, stream>>>(patches, W1, b1, sc1, sh1,
                                                     w2bf, sc2, sh2, w3bf, b3, out);
}

// Round 8
// 634.447 us; speedup vs baseline: 1.3158x; 1.2718x over previous
//
#include <hip/hip_runtime.h>
#include <hip/hip_bf16.h>

// Problem constants
#define B_  64
#define N_  16384
#define S_  64      // NUM_PATCHES
#define K_  32      // PATCH_POINTS
#define C1_ 64
#define C2_ 128
#define C3_ 384
#define R_  (B_*S_*K_)   // 131072 rows
#define BN_EPS_ 1e-5f

// ws layout (float offsets)
#define PATCH_OFF 0
#define CENT_OFF  (R_*3)                      // 393216
#define NB1_ 512
#define P1_OFF    (CENT_OFF + B_*S_*3)        // 405504 (mom: 48*9 floats)
#define SC1_OFF   (P1_OFF + NB1_*C1_*2)       // 471040
#define NB2_ 512
#define P2_OFF    (SC1_OFF + 2*C1_)           // 471168
#define SC2_OFF   (P2_OFF + NB2_*C2_*2)       // 602240
#define W2BF_OFF  (SC2_OFF + 2*C2_)           // 602496 (floats; holds 8192 shorts)
#define W3BF_OFF  (W2BF_OFF + 4096)           // 606592 (floats; holds 49152 shorts)
// end = 631168 floats (~2.52 MB)

#define MOMB_ 48   // moment-kernel blocks

typedef short bf16x8 __attribute__((ext_vector_type(8)));
typedef float f32x4  __attribute__((ext_vector_type(4)));

static __device__ __forceinline__ unsigned short f2bf(float f) {
  unsigned u = __float_as_uint(f);
  unsigned r = (u + 0x7fffu + ((u >> 16) & 1u)) >> 16;   // RNE
  return (unsigned short)r;
}

static __device__ __forceinline__ unsigned fToKey(float d) {
  unsigned u = __float_as_uint(d);
  return (u & 0x80000000u) ? ~u : (u | 0x80000000u);
}
static __device__ __forceinline__ float keyToF(unsigned k) {
  return (k & 0x80000000u) ? __uint_as_float(k & 0x7fffffffu)
                           : -__uint_as_float(~k);
}

// ---------------------------------------------------------------------------
// prep: convert W2 (128x64) and W3 (384x128) to bf16, row-major (plain).
// ---------------------------------------------------------------------------
__global__ void prep_kernel(const float* __restrict__ W2, const float* __restrict__ W3,
                            short* __restrict__ w2bf, short* __restrict__ w3bf) {
  int i = blockIdx.x * 256 + threadIdx.x;
  if (i < C2_*C1_) w2bf[i] = (short)f2bf(W2[i]);
  int j = i - C2_*C1_;
  if (j >= 0 && j < C3_*C2_) w3bf[j] = (short)f2bf(W3[j]);
}

// ---------------------------------------------------------------------------
// FPS: one block (1024 threads) per batch. 16 points/thread in registers.
// launch_bounds(1024,4): VGPR cap 128 -> no scratch spill. One barrier/step
// (double-buffered winner slots); final 16-winner reduce is lane-parallel
// (4-step shfl over 16-lane groups). Distance replicates XLA contraction.
// ---------------------------------------------------------------------------
__global__ __launch_bounds__(1024, 4) void fps_kernel(const float* __restrict__ x,
        float* __restrict__ centers, float* __restrict__ outCent) {
  int b = blockIdx.x;
  int t = threadIdx.x;
  const float* xb = x + (size_t)b * N_ * 3;
  float px[16], py[16], pz[16], dist[16];
#pragma unroll
  for (int j = 0; j < 16; ++j) {
    int n = j * 1024 + t;
    px[j] = xb[n*3+0]; py[j] = xb[n*3+1]; pz[j] = xb[n*3+2];
    dist[j] = 1e10f;
  }
  __shared__ float wd[2][16];
  __shared__ int   wi[2][16];
  float cx = xb[0], cy = xb[1], cz = xb[2];
  int lane = t & 63, wv = t >> 6;
  for (int s = 0; s < S_; ++s) {
    if (t == 0) {
      int task = b * S_ + s;
      centers[task*3+0] = cx; centers[task*3+1] = cy; centers[task*3+2] = cz;
      outCent[task*3+0] = cx; outCent[task*3+1] = cy; outCent[task*3+2] = cz;
    }
    float bd = -1.0f; int bn = 0;
#pragma unroll
    for (int j = 0; j < 16; ++j) {
      float dx = px[j]-cx, dy = py[j]-cy, dz = pz[j]-cz;
      float d = __builtin_fmaf(dz, dz, __builtin_fmaf(dy, dy, dx*dx));
      float dm = fminf(dist[j], d);
      dist[j] = dm;
      int n = j*1024 + t;
      if (dm > bd) { bd = dm; bn = n; }
    }
#pragma unroll
    for (int m = 1; m < 64; m <<= 1) {
      float od = __shfl_xor(bd, m, 64); int on = __shfl_xor(bn, m, 64);
      if (od > bd || (od == bd && on < bn)) { bd = od; bn = on; }
    }
    int buf = s & 1;
    if (lane == 0) { wd[buf][wv] = bd; wi[buf][wv] = bn; }
    __syncthreads();
    // lane-parallel reduce of the 16 wave winners (4 shfl steps)
    float vd = wd[buf][lane & 15];
    int   vi = wi[buf][lane & 15];
#pragma unroll
    for (int m = 1; m < 16; m <<= 1) {
      float od = __shfl_xor(vd, m, 64); int oi = __shfl_xor(vi, m, 64);
      if (od > vd || (od == vd && oi < vi)) { vd = od; vi = oi; }
    }
    int gn = vi;
    cx = xb[gn*3+0]; cy = xb[gn*3+1]; cz = xb[gn*3+2];
    // no second barrier: next step writes wd[buf^1]
  }
}

// ---------------------------------------------------------------------------
// query_ball v3: one block (512 threads, 8 waves) per (b,s). Per-wave exact
// top-32 of its 2048 keys — barrier-free: sampled threshold + secant refine
// into window [32,128], ballot-compaction collect, quadratic (key,idx) rank;
// wave-local radix-bisection fallback. Then ONE barrier + 256-candidate
// tournament rank -> exact global top-32 (= reference top_k semantics).
// ---------------------------------------------------------------------------
__global__ __launch_bounds__(512, 4) void qb_kernel(const float* __restrict__ x,
        const float* __restrict__ centers, float* __restrict__ patches) {
  int t = threadIdx.x;
  int lane = t & 63, wv = t >> 6;
  int task = blockIdx.x;
  int b = task >> 6;
  const float* xb = x + (size_t)b * N_ * 3;
  float cx = centers[task*3+0], cy = centers[task*3+1], cz = centers[task*3+2];
  float A = __builtin_fmaf(cz, cz, __builtin_fmaf(cy, cy, cx*cx));

  __shared__ unsigned long long buf64[8][128];   // 8 KB candidate buffers
  __shared__ unsigned long long wtop64[256];     // 2 KB wave top-32s
  __shared__ int winIdx[32];
  __shared__ int sortedIdx[32];

  unsigned key[32];
  unsigned kmin = 0xffffffffu;
#pragma unroll
  for (int j = 0; j < 32; ++j) {
    int n = j * 512 + t;
    float qx = xb[n*3+0], qy = xb[n*3+1], qz = xb[n*3+2];
    float Bn = __builtin_fmaf(qz, qz, __builtin_fmaf(qy, qy, qx*qx));
    float dt = __builtin_fmaf(cz, qz, __builtin_fmaf(cy, qy, cx*qx));
    float d  = __builtin_fmaf(-2.0f, dt, A + Bn);
    unsigned u = __float_as_uint(d);
    unsigned k = (u & 0x80000000u) ? ~u : (u | 0x80000000u);
    key[j] = k;
    kmin = min(kmin, k);
  }
  // wave-min of all keys
#pragma unroll
  for (int m = 1; m < 64; m <<= 1)
    kmin = min(kmin, (unsigned)__shfl_xor((int)kmin, m, 64));
  // sampled threshold: wave-min of key[0] (64 samples of 2048)
  unsigned T0 = key[0];
#pragma unroll
  for (int m = 1; m < 64; m <<= 1)
    T0 = min(T0, (unsigned)__shfl_xor((int)T0, m, 64));

  // countLess helper (inlined): c(K) = #keys < K in wave (uniform result)
  unsigned Tcur = T0;
  int c;
  {
    int cc = 0;
#pragma unroll
    for (int j = 0; j < 32; ++j) cc += (key[j] < Tcur) ? 1 : 0;
#pragma unroll
    for (int m = 1; m < 64; m <<= 1) cc += __shfl_xor(cc, m, 64);
    c = cc;
  }
  float dmin = keyToF(kmin);
  // secant refine toward count ~64, accept [32,128]
  for (int iter = 0; iter < 4 && !(c >= 32 && c <= 128); ++iter) {
    float dcur = keyToF(Tcur);
    if (!(dcur > dmin)) break;                     // degenerate -> fallback
    float cf = fmaxf((float)c, 1.0f);
    float ratio = exp2f(0.66666667f * log2f(64.0f / cf));
    float dnew = dmin + (dcur - dmin) * ratio;
    unsigned Tn = fToKey(dnew);
    if (Tn == Tcur) break;
    Tcur = Tn;
    int cc = 0;
#pragma unroll
    for (int j = 0; j < 32; ++j) cc += (key[j] < Tcur) ? 1 : 0;
#pragma unroll
    for (int m = 1; m < 64; m <<= 1) cc += __shfl_xor(cc, m, 64);
    c = cc;
  }

  int cW = 0;   // candidates in buf64[wv]
  if (c >= 32 && c <= 128) {
    // ballot-compaction collect of {key < Tcur}
    int base = 0;
#pragma unroll
    for (int j = 0; j < 32; ++j) {
      bool p = key[j] < Tcur;
      unsigned long long mk = __ballot(p);
      if (p) {
        int pos = base + (int)__popcll(mk & ((1ull << lane) - 1ull));
        buf64[wv][pos] = ((unsigned long long)key[j] << 32) | (unsigned)(j*512 + t);
      }
      base += (int)__popcll(mk);
    }
    cW = base;
  } else {
    // wave-local radix bisection fallback (rare)
    unsigned a = 0xffffffffu, o = 0u;
#pragma unroll
    for (int j = 0; j < 32; ++j) { a &= key[j]; o |= key[j]; }
#pragma unroll
    for (int m = 1; m < 64; m <<= 1) {
      a &= (unsigned)__shfl_xor((int)a, m, 64);
      o |= (unsigned)__shfl_xor((int)o, m, 64);
    }
    unsigned diff = a ^ o;
    unsigned result = 0u, CAND = 0u;
    bool early = false;
    for (int bit = 31; bit >= 0; --bit) {
      unsigned msk = 1u << bit;
      if (!(diff & msk)) { result |= (a & msk); continue; }
      unsigned tryv = result | msk;
      int cc = 0;
#pragma unroll
      for (int j = 0; j < 32; ++j) cc += (key[j] < tryv) ? 1 : 0;
#pragma unroll
      for (int m = 1; m < 64; m <<= 1) cc += __shfl_xor(cc, m, 64);
      if (cc >= 32 && cc <= 128) { early = true; CAND = tryv; break; }
      if (cc < 32) result = tryv;
    }
    if (early) {
      int base = 0;
#pragma unroll
      for (int j = 0; j < 32; ++j) {
        bool p = key[j] < CAND;
        unsigned long long mk = __ballot(p);
        if (p) {
          int pos = base + (int)__popcll(mk & ((1ull << lane) - 1ull));
          buf64[wv][pos] = ((unsigned long long)key[j] << 32) | (unsigned)(j*512 + t);
        }
        base += (int)__popcll(mk);
      }
      cW = base;
    } else {
      // exact boundary key T = result; collect strict-less then index-ordered ties
      unsigned T = result;
      int base = 0;
#pragma unroll
      for (int j = 0; j < 32; ++j) {
        bool p = key[j] < T;
        unsigned long long mk = __ballot(p);
        if (p) {
          int pos = base + (int)__popcll(mk & ((1ull << lane) - 1ull));
          buf64[wv][pos] = ((unsigned long long)key[j] << 32) | (unsigned)(j*512 + t);
        }
        base += (int)__popcll(mk);
      }
      int cl = base;                 // < 32
      int picked = -1;
      for (int r = 0; r < 32 - cl; ++r) {
        int cand = 0x7fffffff;
#pragma unroll
        for (int j = 0; j < 32; ++j) {
          int n = j*512 + t;
          if (key[j] == T && n > picked && n < cand) cand = n;
        }
#pragma unroll
        for (int m = 1; m < 64; m <<= 1) cand = min(cand, __shfl_xor(cand, m, 64));
        if (lane == 0)
          buf64[wv][cl + r] = ((unsigned long long)T << 32) | (unsigned)cand;
        picked = cand;
      }
      cW = 32;
    }
  }

  // wave rank: top-32 of cW candidates by (key,idx) (packed u64 order)
  {
    unsigned long long my0 = (lane < cW) ? buf64[wv][lane] : ~0ull;
    unsigned long long my1 = (lane + 64 < cW) ? buf64[wv][lane + 64] : ~0ull;
    int r0 = 0, r1 = 0;
    for (int jj = 0; jj < cW; ++jj) {
      unsigned long long ov = buf64[wv][jj];
      r0 += (ov < my0) ? 1 : 0;
      r1 += (ov < my1) ? 1 : 0;
    }
    if (lane < cW && r0 < 32) wtop64[wv*32 + r0] = my0;
    if (lane + 64 < cW && r1 < 32) wtop64[wv*32 + r1] = my1;
  }
  __syncthreads();

  // block tournament: exact top-32 of the 256 wave winners
  if (t < 256) {
    unsigned long long me = wtop64[t];
    int rk = 0;
    for (int jj = 0; jj < 256; ++jj) rk += (wtop64[jj] < me) ? 1 : 0;
    if (rk < 32) winIdx[rk] = (int)(me & 0xffffffffu);
  }
  __syncthreads();
  if (t < 32) {
    int v = winIdx[t];
    int slot = 0;
#pragma unroll
    for (int j = 0; j < 32; ++j) slot += (winIdx[j] < v) ? 1 : 0;
    sortedIdx[slot] = v;
  }
  __syncthreads();
  if (t < 32) {
    int n = sortedIdx[t];
    float qx = xb[n*3+0], qy = xb[n*3+1], qz = xb[n*3+2];
    size_t row = (size_t)task * K_ + t;
    patches[row*3+0] = qx - cx;
    patches[row*3+1] = qy - cy;
    patches[row*3+2] = qz - cz;
  }
}

// ---------------------------------------------------------------------------
// mom: 9 moments of patches (Sx,Sy,Sz,Sxx,Syy,Szz,Sxy,Sxz,Syz) -> mom[48][9]
// (h1 is affine in p, so layer-1 BN stats follow algebraically in finalize1.)
// ---------------------------------------------------------------------------
__global__ __launch_bounds__(256) void mom_kernel(const float* __restrict__ patches,
        float* __restrict__ mom) {
  int t = threadIdx.x;
  float s[9] = {0,0,0,0,0,0,0,0,0};
  for (int r = blockIdx.x*256 + t; r < R_; r += MOMB_*256) {
    const float* p = patches + (size_t)r*3;
    float x0 = p[0], y0 = p[1], z0 = p[2];
    s[0] += x0; s[1] += y0; s[2] += z0;
    s[3] += x0*x0; s[4] += y0*y0; s[5] += z0*z0;
    s[6] += x0*y0; s[7] += x0*z0; s[8] += y0*z0;
  }
  __shared__ float red[4][9];
  int lane = t & 63, wv = t >> 6;
#pragma unroll
  for (int k = 0; k < 9; ++k) {
    float v = s[k];
#pragma unroll
    for (int m = 1; m < 64; m <<= 1) v += __shfl_xor(v, m, 64);
    if (lane == 0) red[wv][k] = v;
  }
  __syncthreads();
  if (t < 9) mom[blockIdx.x*9 + t] = red[0][t] + red[1][t] + red[2][t] + red[3][t];
}

// ---------------------------------------------------------------------------
// finalize1: layer-1 BN scale/shift from the 9 moments (double combine).
// ---------------------------------------------------------------------------
__global__ void finalize1_kernel(const float* __restrict__ mom,
        const float* __restrict__ W1, const float* __restrict__ b1,
        const float* __restrict__ g, const float* __restrict__ be,
        float* __restrict__ scale, float* __restrict__ shift) {
  int o = threadIdx.x;
  __shared__ double M[9];
  if (o < 9) {
    double ss = 0.0;
    for (int i = 0; i < MOMB_; ++i) ss += (double)mom[i*9 + o];
    M[o] = ss;
  }
  __syncthreads();
  if (o >= C1_) return;
  double w0 = W1[o*3], w1 = W1[o*3+1], w2 = W1[o*3+2], bb = b1[o];
  double wSp = w0*M[0] + w1*M[1] + w2*M[2];
  double s1 = wSp + (double)R_*bb;
  double s2 = w0*w0*M[3] + w1*w1*M[4] + w2*w2*M[5]
            + 2.0*(w0*w1*M[6] + w0*w2*M[7] + w1*w2*M[8])
            + 2.0*bb*wSp + (double)R_*bb*bb;
  float m   = (float)(s1 / (double)R_);
  float eh2 = (float)(s2 / (double)R_);
  float v = eh2 - m*m;
  float rs = rsqrtf(v + BN_EPS_);
  float sc = g[o] * rs;
  scale[o] = sc;
  shift[o] = be[o] - m*sc;
}

// ---------------------------------------------------------------------------
// finalize: deterministic sum of partials -> scale/shift (BN affine form).
// If bias != nullptr, folds a pre-BN linear bias into shift.
// ---------------------------------------------------------------------------
__global__ void finalize_kernel(const float* __restrict__ part, int nblk, int nch,
        const float* __restrict__ g, const float* __restrict__ be,
        const float* __restrict__ bias,
        float* __restrict__ scale, float* __restrict__ shift) {
  int o = threadIdx.x;
  if (o >= nch) return;
  double s1 = 0.0, s2 = 0.0;
  for (int i = 0; i < nblk; ++i) {
    s1 += (double)part[i*nch*2 + o*2 + 0];
    s2 += (double)part[i*nch*2 + o*2 + 1];
  }
  float m   = (float)(s1 / (double)R_);
  float eh2 = (float)(s2 / (double)R_);
  float v = eh2 - m*m;
  float rs = rsqrtf(v + BN_EPS_);
  float sc = g[o] * rs;
  scale[o] = sc;
  float sh = be[o] - m*sc;
  if (bias) sh += bias[o]*sc;
  shift[o] = sh;
}

// ---------------------------------------------------------------------------
// stats2: 512 blocks x 256 rows (2 tiles of 128): recompute a1 tile (LDS),
// h2 = a1@W2^T + b2 (fp32), per-channel sum/sumsq.
// ---------------------------------------------------------------------------
__global__ __launch_bounds__(256) void stats2_kernel(const float* __restrict__ patches,
        const float* __restrict__ W1, const float* __restrict__ b1,
        const float* __restrict__ sc1, const float* __restrict__ sh1,
        const float* __restrict__ W2, const float* __restrict__ b2,
        float* __restrict__ part) {
  __shared__ float a1L[128][68];
  __shared__ float red[2][128][2];
  int t = threadIdx.x;
  float4 wreg[16];
  const float4* w2r = (const float4*)(W2 + (t & 127)*64);
#pragma unroll
  for (int c = 0; c < 16; ++c) wreg[c] = w2r[c];
  float bb = b2[t & 127];
  float s1 = 0.f, s2 = 0.f;
  int rg = t >> 7;
  for (int tile = 0; tile < 2; ++tile) {
    int r0 = blockIdx.x * 256 + tile * 128;
    {
      int r = t & 127, oh = t >> 7;
      const float* p = patches + (size_t)(r0 + r) * 3;
      float p0 = p[0], p1 = p[1], p2 = p[2];
#pragma unroll
      for (int j = 0; j < 32; ++j) {
        int o = oh*32 + j;
        float h = p0*W1[o*3] + p1*W1[o*3+1] + p2*W1[o*3+2] + b1[o];
        a1L[r][o] = fmaxf(h*sc1[o] + sh1[o], 0.f);
      }
    }
    __syncthreads();
    for (int i = 0; i < 64; ++i) {
      int r = rg*64 + i;
      float acc = bb;
      const float4* a4 = (const float4*)(&a1L[r][0]);
#pragma unroll
      for (int c = 0; c < 16; ++c) {
        float4 a = a4[c];
        acc += a.x*wreg[c].x; acc += a.y*wreg[c].y;
        acc += a.z*wreg[c].z; acc += a.w*wreg[c].w;
      }
      s1 += acc; s2 += acc*acc;
    }
    __syncthreads();
  }
  red[rg][t & 127][0] = s1; red[rg][t & 127][1] = s2;
  __syncthreads();
  if (t < 128) {
    part[blockIdx.x*256 + t*2 + 0] = red[0][t][0] + red[1][t][0];
    part[blockIdx.x*256 + t*2 + 1] = red[0][t][1] + red[1][t][1];
  }
}

// ---------------------------------------------------------------------------
// embed (MFMA): 4 tasks/block (M=128 rows), 256 threads (4 waves, 1 task/wave).
// ---------------------------------------------------------------------------
__global__ __launch_bounds__(256) void embed_kernel(
        const float* __restrict__ patches,
        const float* __restrict__ W1, const float* __restrict__ b1,
        const float* __restrict__ sc1, const float* __restrict__ sh1,
        const short* __restrict__ w2bf, const float* __restrict__ sc2,
        const float* __restrict__ sh2f,
        const short* __restrict__ w3bf, const float* __restrict__ b3,
        float* __restrict__ out) {
  __shared__ char lds[49152];   // a1L @0 (16KB), a2L @16384 (32KB)
  int t = threadIdx.x;
  int l = t & 63, w = t >> 6;
  int lo = l & 15, hi = l >> 4;

  // ---- P1 ----
  {
    int row = t >> 1, half = t & 1;
    const float* p = patches + ((size_t)blockIdx.x*128 + row)*3;
    float p0 = p[0], p1 = p[1], p2 = p[2];
    int swz = (row & 7) << 4;
    char* dst = lds + row*128;
#pragma unroll
    for (int g = 0; g < 4; ++g) {
      unsigned short pk[8];
#pragma unroll
      for (int j = 0; j < 8; ++j) {
        int o = half*32 + g*8 + j;
        float h = p0*W1[o*3] + p1*W1[o*3+1] + p2*W1[o*3+2] + b1[o];
        pk[j] = f2bf(fmaxf(h*sc1[o] + sh1[o], 0.f));
      }
      int4 v;
      v.x = pk[0] | (pk[1]<<16); v.y = pk[2] | (pk[3]<<16);
      v.z = pk[4] | (pk[5]<<16); v.w = pk[6] | (pk[7]<<16);
      *(int4*)(dst + (((half*64 + g*16)) ^ swz)) = v;
    }
  }
  __syncthreads();

  // ---- P2 ----
  {
    bf16x8 af[2][2];
#pragma unroll
    for (int mt = 0; mt < 2; ++mt) {
      int row = w*32 + mt*16 + lo;
#pragma unroll
      for (int ks = 0; ks < 2; ++ks)
        af[mt][ks] = *(const bf16x8*)(lds + row*128 + ((ks*64 + hi*16) ^ ((row&7)<<4)));
    }
#pragma unroll
    for (int nt = 0; nt < 8; ++nt) {
      f32x4 acc0 = {0.f,0.f,0.f,0.f}, acc1 = {0.f,0.f,0.f,0.f};
      int n = nt*16 + lo;
#pragma unroll
      for (int ks = 0; ks < 2; ++ks) {
        bf16x8 bfv = *(const bf16x8*)(w2bf + n*64 + ks*32 + hi*8);
        acc0 = __builtin_amdgcn_mfma_f32_16x16x32_bf16(af[0][ks], bfv, acc0, 0, 0, 0);
        acc1 = __builtin_amdgcn_mfma_f32_16x16x32_bf16(af[1][ks], bfv, acc1, 0, 0, 0);
      }
      float sc = sc2[n], sh = sh2f[n];
#pragma unroll
      for (int mt = 0; mt < 2; ++mt) {
        f32x4 c = mt ? acc1 : acc0;
#pragma unroll
        for (int r = 0; r < 4; ++r) {
          int row = w*32 + mt*16 + hi*4 + r;
          unsigned short v = f2bf(fmaxf(c[r]*sc + sh, 0.f));
          *(short*)(lds + 16384 + row*256 + ((n*2) ^ ((row&7)<<4))) = (short)v;
        }
      }
    }
  }
  __syncthreads();

  // ---- P3 ----
  {
    bf16x8 af[2][4];
#pragma unroll
    for (int mt = 0; mt < 2; ++mt) {
      int row = w*32 + mt*16 + lo;
#pragma unroll
      for (int ks = 0; ks < 4; ++ks)
        af[mt][ks] = *(const bf16x8*)(lds + 16384 + row*256 + ((ks*64 + hi*16) ^ ((row&7)<<4)));
    }
    size_t gtask = (size_t)blockIdx.x*4 + w;
#pragma unroll 4
    for (int nt = 0; nt < 24; ++nt) {
      f32x4 acc0 = {0.f,0.f,0.f,0.f}, acc1 = {0.f,0.f,0.f,0.f};
      int e = nt*16 + lo;
#pragma unroll
      for (int ks = 0; ks < 4; ++ks) {
        bf16x8 bfv = *(const bf16x8*)(w3bf + e*128 + ks*32 + hi*8);
        acc0 = __builtin_amdgcn_mfma_f32_16x16x32_bf16(af[0][ks], bfv, acc0, 0, 0, 0);
        acc1 = __builtin_amdgcn_mfma_f32_16x16x32_bf16(af[1][ks], bfv, acc1, 0, 0, 0);
      }
      float m0 = fmaxf(fmaxf(acc0[0], acc0[1]), fmaxf(acc0[2], acc0[3]));
      float m1 = fmaxf(fmaxf(acc1[0], acc1[1]), fmaxf(acc1[2], acc1[3]));
      float m = fmaxf(m0, m1);
      m = fmaxf(m, __shfl_xor(m, 16, 64));
      m = fmaxf(m, __shfl_xor(m, 32, 64));
      if (l < 16) out[gtask*C3_ + e] = m + b3[e];
    }
  }
}

// ---------------------------------------------------------------------------
extern "C" void kernel_launch(void* const* d_in, const int* in_sizes, int n_in,
                              void* d_out, int out_size, void* d_ws, size_t ws_size,
                              hipStream_t stream) {
  (void)in_sizes; (void)n_in; (void)out_size; (void)ws_size;
  const float* x   = (const float*)d_in[0];
  const float* W1  = (const float*)d_in[1];
  const float* b1  = (const float*)d_in[2];
  const float* g1  = (const float*)d_in[3];
  const float* be1 = (const float*)d_in[4];
  const float* W2  = (const float*)d_in[5];
  const float* b2  = (const float*)d_in[6];
  const float* g2  = (const float*)d_in[7];
  const float* be2 = (const float*)d_in[8];
  const float* W3  = (const float*)d_in[9];
  const float* b3  = (const float*)d_in[10];
  float* out = (float*)d_out;
  float* ws  = (float*)d_ws;

  float* patches = ws + PATCH_OFF;
  float* centers = ws + CENT_OFF;
  float* mom1    = ws + P1_OFF;
  float* sc1     = ws + SC1_OFF; float* sh1 = sc1 + C1_;
  float* part2   = ws + P2_OFF;
  float* sc2     = ws + SC2_OFF; float* sh2 = sc2 + C2_;
  short* w2bf    = (short*)(ws + W2BF_OFF);
  short* w3bf    = (short*)(ws + W3BF_OFF);
  float* outCent = out + (size_t)B_*S_*C3_;

  prep_kernel<<<dim3((C2_*C1_ + C3_*C2_)/256), dim3(256), 0, stream>>>(W2, W3, w2bf, w3bf);
  fps_kernel<<<dim3(B_), dim3(1024), 0, stream>>>(x, centers, outCent);
  qb_kernel<<<dim3(4096), dim3(512), 0, stream>>>(x, centers, patches);
  mom_kernel<<<dim3(MOMB_), dim3(256), 0, stream>>>(patches, mom1);
  finalize1_kernel<<<dim3(1), dim3(64), 0, stream>>>(mom1, W1, b1, g1, be1, sc1, sh1);
  stats2_kernel<<<dim3(NB2_), dim3(256), 0, stream>>>(patches, W1, b1, sc1, sh1, W2, b2, part2);
  finalize_kernel<<<dim3(1), dim3(128), 0, stream>>>(part2, NB2_, C2_, g2, be2, b2, sc2, sh2);
  embed_kernel<<<dim3(1024), dim3(256), 0, stream>>>(patches, W1, b1, sc1, sh1,
                                                     w2bf, sc2, sh2, w3bf, b3, out);
}